// Round 8
// baseline (156.218 us; speedup 1.0000x reference)
//
#include <hip/hip_runtime.h>
#include <math.h>

typedef __bf16 bf16x8 __attribute__((ext_vector_type(8)));
typedef float  f32x4  __attribute__((ext_vector_type(4)));
typedef int    i32x4  __attribute__((ext_vector_type(4)));

#define MFMA16(a, b, c) __builtin_amdgcn_mfma_f32_16x16x32_bf16((a), (b), (c), 0, 0, 0)

// A-tile: row stride 128 elements, 16B chunks XOR-swizzled by row.
#define ATIDX(r, c) ((r) * 128 + (((c) ^ ((r) & 7)) * 8))

// ---------------------------------------------------------------------------
// setup: blocks [0,1024) xpose NCHW->NHWC bf16; [1024,1056) wFragD transform
// (LDS-staged, coalesced both directions); [1056,1064) wFragO + BN fold.
// ---------------------------------------------------------------------------
__global__ __launch_bounds__(256) void setup_kernel(
    const float* __restrict__ x, const float* __restrict__ w,
    const float* __restrict__ w_off, const float* __restrict__ bconv,
    const float* __restrict__ gamma, const float* __restrict__ beta,
    const float* __restrict__ mean, const float* __restrict__ var,
    __bf16* __restrict__ xT, __bf16* __restrict__ wFragD,
    __bf16* __restrict__ wFragO, float* __restrict__ sc,
    float* __restrict__ sh) {
  __shared__ float ws[16 * 128 * 9];   // 73.7 KB; xpose uses first 64*65
  int t = threadIdx.x;
  if (blockIdx.x < 1024) {
    int b = blockIdx.x >> 8, y = (blockIdx.x >> 2) & 63, cc = blockIdx.x & 3;
    for (int i = t; i < 4096; i += 256) {
      int cl = i >> 6, xc = i & 63;
      ws[cl * 65 + xc] = x[(((size_t)b * 256 + cc * 64 + cl) * 64 + y) * 64 + xc];
    }
    __syncthreads();
    for (int i = t; i < 4096; i += 256) {
      int xc = i >> 6, cl = i & 63;
      xT[(((size_t)b * 64 + y) * 64 + xc) * 256 + cc * 64 + cl] =
          (__bf16)ws[cl * 65 + xc];
    }
    return;
  }
  if (blockIdx.x < 1056) {
    int id = blockIdx.x - 1024;
    int g = id >> 4, ocb = id & 15;
    // coalesced load: 16 oc x (128 ci x 9 taps) contiguous spans
    for (int i = t; i < 18432; i += 256) {
      int oc_l = i / 1152, rem = i % 1152;
      ws[oc_l * 1152 + rem] = w[(size_t)(ocb * 16 + oc_l) * 2304 + g * 1152 + rem];
    }
    __syncthreads();
    // coalesced store: 1KB fragment chunks
    for (int i = t; i < 18432; i += 256) {
      int j = i & 7, lane8 = (i >> 3) & 63, kc = (i >> 9) & 3, ktap = i >> 11;
      int klocal = (lane8 >> 4) * 8 + j;
      int oc_l = lane8 & 15, ci_l = kc * 32 + klocal;
      float v = ws[oc_l * 1152 + ci_l * 9 + ktap];
      int gk = g * 9 + ktap;
      wFragD[((size_t)(gk * 4 + kc) * 16 + ocb) * 512 + (i & 511)] = (__bf16)v;
    }
    return;
  }
  {
    int id2 = blockIdx.x - 1056;
    int ocb = id2 >> 1, h = id2 & 1;
    for (int i = t; i < 18432; i += 256) {
      int oc_l = i / 1152, rem = i % 1152;
      int oc = ocb * 16 + oc_l;
      ws[oc_l * 1152 + rem] =
          (oc < 54) ? w_off[(size_t)oc * 2304 + h * 1152 + rem] : 0.f;
    }
    __syncthreads();
    for (int i = t; i < 18432; i += 256) {
      int j = i & 7, lane8 = (i >> 3) & 63, kcl = (i >> 9) & 3, ktap = i >> 11;
      int klocal = (lane8 >> 4) * 8 + j;
      int oc_l = lane8 & 15, ci_l = kcl * 32 + klocal;
      int kc = h * 4 + kcl;
      float v = ws[oc_l * 1152 + ci_l * 9 + ktap];
      wFragO[((size_t)(ktap * 8 + kc) * 4 + ocb) * 512 + (i & 511)] = (__bf16)v;
    }
    if (id2 == 0 && t < 256) {
      float s = gamma[t] * rsqrtf(var[t] + 1e-5f);
      sc[t] = s;
      sh[t] = (bconv[t] - mean[t]) * s + beta[t];
    }
  }
}

// ---------------------------------------------------------------------------
// fused kernel: 1024 thr / 16 waves per (b,y) row.
//   A: stage 3 padded rows; 9-tap MFMA offset-conv (16 waves = 4 mq x 4 ocq)
//   B: bilinear tables
//   C: producer/consumer split — waves 0-7 gather tap gk+1, waves 8-15 MFMA
//      tap gk (M=64 x N=32 each, rolling B prefetch). One barrier per tap.
// ---------------------------------------------------------------------------
struct PhaseC {
  f32x4 swgtv[18 * 64];
  i32x4 slinv[18 * 64];
  __bf16 atile[2][64 * 128];
};
union FusedLDS {
  __bf16 rowbuf[3 * 66 * 256];
  PhaseC c;
};

__global__ __launch_bounds__(1024) void fused_kernel(
    const __bf16* __restrict__ xT, const __bf16* __restrict__ wFragD,
    const __bf16* __restrict__ wFragO, const float* __restrict__ b_off,
    const float* __restrict__ sc, const float* __restrict__ sh,
    float* __restrict__ out) {
  __shared__ __attribute__((aligned(16))) FusedLDS U;
  __shared__ float omrow[54 * 64];
  int t = threadIdx.x;
  int b = blockIdx.x >> 6, y = blockIdx.x & 63;
  int lane = t & 63, wv = t >> 6;
  int l15 = lane & 15, quad = lane >> 4;
  const __bf16* xTb = xT + (size_t)b * 64 * 64 * 256;
  bf16x8 z8;
  #pragma unroll
  for (int e = 0; e < 8; ++e) z8[e] = (__bf16)0.f;

  // ---- phase A: stage rowbuf[dy][px66][ch] ----
  for (int i = t; i < 3 * 66 * 32; i += 1024) {
    int c = i & 31, px66 = (i >> 5) % 66, dy = i / 2112;
    int y2 = y + dy - 1, x2 = px66 - 1;
    bf16x8 v = z8;
    if (y2 >= 0 && y2 < 64 && x2 >= 0 && x2 < 64)
      v = *(const bf16x8*)(xTb + ((size_t)y2 * 64 + x2) * 256 + c * 8);
    *(bf16x8*)&U.rowbuf[dy * 16896 + px66 * 256 + ((c ^ (px66 & 7)) * 8)] = v;
  }
  __syncthreads();

  // offset-conv: 16 waves = 4 m-quarters x 4 oc-slices, 1 acc frag each
  {
    int mq = wv & 3, ocq = wv >> 2;
    f32x4 acc0 = {0.f, 0.f, 0.f, 0.f};
    for (int tap = 0; tap < 9; ++tap) {
      int dy = tap / 3, dxs = tap % 3;
      const __bf16* bb = wFragO + ((size_t)(tap * 8) * 4 + ocq) * 512 + lane * 8;
      bf16x8 Bf[8];
      #pragma unroll
      for (int kc = 0; kc < 8; ++kc)
        Bf[kc] = *(const bf16x8*)(bb + (size_t)kc * 4 * 512);
      int p0 = mq * 16 + l15 + dxs;
      const __bf16* rb = U.rowbuf + dy * 16896;
      #pragma unroll
      for (int kc = 0; kc < 8; ++kc) {
        int c = kc * 4 + quad;
        bf16x8 a0 = *(const bf16x8*)&rb[p0 * 256 + ((c ^ (p0 & 7)) * 8)];
        acc0 = MFMA16(a0, Bf[kc], acc0);
      }
    }
    int oc = ocq * 16 + l15;
    if (oc < 54) {
      float bo = b_off[oc];
      f32x4 r = {acc0.x + bo, acc0.y + bo, acc0.z + bo, acc0.w + bo};
      *(f32x4*)&omrow[oc * 64 + mq * 16 + quad * 4] = r;
    }
  }
  __syncthreads();                        // omrow ready; rowbuf dead

  // ---- phase B: bilinear corner tables ----
  for (int i = t; i < 18 * 64; i += 1024) {
    int gk = i >> 6, p = i & 63;
    int k = gk % 9;
    float oy = omrow[gk * 64 + p];
    float ox = omrow[(18 + gk) * 64 + p];
    float mz = omrow[(36 + gk) * 64 + p];
    float mv = 1.f / (1.f + expf(-mz));
    float py  = (float)(y + (k / 3) - 1) + oy;
    float pxf = (float)(p + (k % 3) - 1) + ox;
    float y0f = floorf(py), x0f = floorf(pxf);
    int y0 = (int)y0f, x0 = (int)x0f;
    float ly = py - y0f, lx = pxf - x0f;
    int y1 = y0 + 1, x1 = x0 + 1;
    bool vy0 = (y0 >= 0) && (y0 < 64), vy1 = (y1 >= 0) && (y1 < 64);
    bool vx0 = (x0 >= 0) && (x0 < 64), vx1 = (x1 >= 0) && (x1 < 64);
    int cy0 = min(max(y0, 0), 63), cy1 = min(max(y1, 0), 63);
    int cx0 = min(max(x0, 0), 63), cx1 = min(max(x1, 0), 63);
    f32x4 sv;
    sv.x = (vy0 && vx0) ? (1.f - ly) * (1.f - lx) * mv : 0.f;
    sv.y = (vy0 && vx1) ? (1.f - ly) * lx * mv : 0.f;
    sv.z = (vy1 && vx0) ? ly * (1.f - lx) * mv : 0.f;
    sv.w = (vy1 && vx1) ? ly * lx * mv : 0.f;
    i32x4 lv;
    lv.x = (cy0 * 64 + cx0) * 256;
    lv.y = (cy0 * 64 + cx1) * 256;
    lv.z = (cy1 * 64 + cx0) * 256;
    lv.w = (cy1 * 64 + cx1) * 256;
    U.c.swgtv[i] = sv;
    U.c.slinv[i] = lv;
  }
  __syncthreads();                        // tables visible; atile region free

  // ---- phase C prologue: all 1024 threads gather tap 0 (1 chunk each) ----
  {
    int p = t >> 4, c16 = t & 15;
    const __bf16* xg = xTb + c16 * 8;     // tap 0 -> group 0
    f32x4 sv = U.c.swgtv[p];
    i32x4 lv = U.c.slinv[p];
    bf16x8 c0 = *(const bf16x8*)(xg + lv.x);
    bf16x8 c1 = *(const bf16x8*)(xg + lv.y);
    bf16x8 c2 = *(const bf16x8*)(xg + lv.z);
    bf16x8 c3 = *(const bf16x8*)(xg + lv.w);
    bf16x8 o;
    #pragma unroll
    for (int e = 0; e < 8; ++e)
      o[e] = (__bf16)(sv.x * (float)c0[e] + sv.y * (float)c1[e]
                    + sv.z * (float)c2[e] + sv.w * (float)c3[e]);
    *(bf16x8*)&U.c.atile[0][ATIDX(p, c16)] = o;
  }

  f32x4 acc[4][2];
  #pragma unroll
  for (int fm = 0; fm < 4; ++fm) {
    acc[fm][0] = (f32x4){0.f, 0.f, 0.f, 0.f};
    acc[fm][1] = (f32x4){0.f, 0.f, 0.f, 0.f};
  }
  int nq = wv - 8;
  bf16x8 bn0, bn1;
  if (wv >= 8) {                          // consumer: rolling B prefetch (idx 0)
    const __bf16* bb = wFragD + ((size_t)nq * 2) * 512 + lane * 8;
    bn0 = *(const bf16x8*)bb;
    bn1 = *(const bf16x8*)(bb + 512);
  }
  __syncthreads();                        // atile[0] (tap 0) ready

  // ---- phase C main loop: 1 tap per barrier; producers gather gk+1 ----
  for (int gk = 0; gk < 18; ++gk) {
    if (wv < 8) {
      if (gk < 17) {
        int gn = gk + 1;
        int c16 = t & 15, p = t >> 4;     // p in [0,32); also handles p+32
        const __bf16* xg = xTb + (gn / 9) * 128 + c16 * 8;
        __bf16* dst = U.c.atile[(gk + 1) & 1];
        #pragma unroll
        for (int half = 0; half < 2; ++half) {
          int pp = p + half * 32;
          f32x4 sv = U.c.swgtv[gn * 64 + pp];
          i32x4 lv = U.c.slinv[gn * 64 + pp];
          bf16x8 c0 = *(const bf16x8*)(xg + lv.x);
          bf16x8 c1 = *(const bf16x8*)(xg + lv.y);
          bf16x8 c2 = *(const bf16x8*)(xg + lv.z);
          bf16x8 c3 = *(const bf16x8*)(xg + lv.w);
          bf16x8 o;
          #pragma unroll
          for (int e = 0; e < 8; ++e)
            o[e] = (__bf16)(sv.x * (float)c0[e] + sv.y * (float)c1[e]
                          + sv.z * (float)c2[e] + sv.w * (float)c3[e]);
          *(bf16x8*)&dst[ATIDX(pp, c16)] = o;
        }
      }
    } else {
      const __bf16* at = U.c.atile[gk & 1];
      #pragma unroll
      for (int kc = 0; kc < 4; ++kc) {
        bf16x8 b0 = bn0, b1 = bn1;
        int nidx = gk * 4 + kc + 1;
        if (nidx < 72) {                  // prefetch next B pair
          const __bf16* bb = wFragD + ((size_t)nidx * 16 + nq * 2) * 512 + lane * 8;
          bn0 = *(const bf16x8*)bb;
          bn1 = *(const bf16x8*)(bb + 512);
        }
        #pragma unroll
        for (int fm = 0; fm < 4; ++fm) {
          bf16x8 a = *(const bf16x8*)&at[ATIDX(fm * 16 + l15, kc * 4 + quad)];
          acc[fm][0] = MFMA16(a, b0, acc[fm][0]);
          acc[fm][1] = MFMA16(a, b1, acc[fm][1]);
        }
      }
    }
    __syncthreads();
  }

  // ---- epilogue: consumers write BN+ReLU output ----
  if (wv >= 8) {
    #pragma unroll
    for (int fm = 0; fm < 4; ++fm) {
      #pragma unroll
      for (int fn = 0; fn < 2; ++fn) {
        int oc = nq * 32 + fn * 16 + l15;
        float s = sc[oc], h = sh[oc];
        f32x4 v = acc[fm][fn];
        f32x4 r = {fmaxf(v.x * s + h, 0.f), fmaxf(v.y * s + h, 0.f),
                   fmaxf(v.z * s + h, 0.f), fmaxf(v.w * s + h, 0.f)};
        int pxs = fm * 16 + quad * 4;
        *(f32x4*)(out + (((size_t)b * 256 + oc) * 64 + y) * 64 + pxs) = r;
      }
    }
  }
}

// ---------------------------------------------------------------------------
extern "C" void kernel_launch(void* const* d_in, const int* in_sizes, int n_in,
                              void* d_out, int out_size, void* d_ws, size_t ws_size,
                              hipStream_t stream) {
  const float* x     = (const float*)d_in[0];
  const float* w_off = (const float*)d_in[1];
  const float* b_off = (const float*)d_in[2];
  const float* w     = (const float*)d_in[3];
  const float* bconv = (const float*)d_in[4];
  const float* gamma = (const float*)d_in[5];
  const float* beta  = (const float*)d_in[6];
  const float* rmean = (const float*)d_in[7];
  const float* rvar  = (const float*)d_in[8];
  float* out = (float*)d_out;

  __bf16* xT     = (__bf16*)d_ws;                          // 8,388,608 B
  __bf16* wFragD = (__bf16*)((char*)d_ws + 8388608);       // 1,179,648 B
  __bf16* wFragO = (__bf16*)((char*)d_ws + 9568256);       //   294,912 B
  float*  sc     = (float*)((char*)d_ws + 9863168);
  float*  sh     = (float*)((char*)d_ws + 9864192);

  setup_kernel<<<1064, 256, 0, stream>>>(
      x, w, w_off, bconv, gamma, beta, rmean, rvar, xT, wFragD, wFragO, sc, sh);
  fused_kernel<<<4 * 64, 1024, 0, stream>>>(xT, wFragD, wFragO, b_off, sc, sh, out);
}

// Round 9
// 131.876 us; speedup vs baseline: 1.1846x; 1.1846x over previous
//
#include <hip/hip_runtime.h>
#include <math.h>

typedef __bf16 bf16x8 __attribute__((ext_vector_type(8)));
typedef float  f32x4  __attribute__((ext_vector_type(4)));
typedef int    i32x4  __attribute__((ext_vector_type(4)));

#define MFMA16(a, b, c) __builtin_amdgcn_mfma_f32_16x16x32_bf16((a), (b), (c), 0, 0, 0)

// A-tile: row stride 128 elements, 16B chunks XOR-swizzled by row.
#define ATIDX(r, c) ((r) * 128 + (((c) ^ ((r) & 7)) * 8))

// ---------------------------------------------------------------------------
// setup (r7 form, small LDS): blocks [0,1024) xpose; [1024,3904) weight
// transforms elementwise + BN fold. 16.6 KB LDS -> high occupancy.
// ---------------------------------------------------------------------------
__global__ __launch_bounds__(256) void setup_kernel(
    const float* __restrict__ x, const float* __restrict__ w,
    const float* __restrict__ w_off, const float* __restrict__ bconv,
    const float* __restrict__ gamma, const float* __restrict__ beta,
    const float* __restrict__ mean, const float* __restrict__ var,
    __bf16* __restrict__ xT, __bf16* __restrict__ wFragD,
    __bf16* __restrict__ wFragO, float* __restrict__ sc,
    float* __restrict__ sh) {
  __shared__ float xs[64][65];
  int t = threadIdx.x;
  if (blockIdx.x < 1024) {
    int b = blockIdx.x >> 8, y = (blockIdx.x >> 2) & 63, cc = blockIdx.x & 3;
    for (int i = t; i < 4096; i += 256) {
      int cl = i >> 6, xc = i & 63;
      xs[cl][xc] = x[(((size_t)b * 256 + cc * 64 + cl) * 64 + y) * 64 + xc];
    }
    __syncthreads();
    for (int i = t; i < 4096; i += 256) {
      int xc = i >> 6, cl = i & 63;
      xT[(((size_t)b * 64 + y) * 64 + xc) * 256 + cc * 64 + cl] = (__bf16)xs[cl][xc];
    }
    return;
  }
  int i = (blockIdx.x - 1024) * 256 + t;
  if (i < 589824) {
    int j = i & 7, lane = (i >> 3) & 63, ocb = (i >> 9) & 15;
    int kc = (i >> 13) & 3, gk = i >> 15;
    int klocal = (lane >> 4) * 8 + j;
    int oc = ocb * 16 + (lane & 15);
    int c = kc * 32 + klocal;
    int g = gk / 9, ktap = gk % 9;
    wFragD[i] = (__bf16)w[((size_t)oc * 256 + g * 128 + c) * 9 + ktap];
  } else {
    int i2 = i - 589824;
    int j = i2 & 7, lane = (i2 >> 3) & 63, ocb = (i2 >> 9) & 3;
    int kc = (i2 >> 11) & 7, tap = i2 >> 14;
    int klocal = (lane >> 4) * 8 + j;
    int oc = ocb * 16 + (lane & 15);
    int ci = kc * 32 + klocal;
    wFragO[i2] = (oc < 54) ? (__bf16)w_off[((size_t)oc * 256 + ci) * 9 + tap]
                           : (__bf16)0.f;
  }
  if (i < 256) {
    float s = gamma[i] * rsqrtf(var[i] + 1e-5f);
    sc[i] = s;
    sh[i] = (bconv[i] - mean[i]) * s + beta[i];
  }
}

// ---------------------------------------------------------------------------
// fused kernel: 1024 thr / 16 waves per (b,y) row.
//   A: stage 3 padded rows; offset-conv on 4 waves (wv=ocq, 4 M-frags each)
//      -> wFragO read once per block, not 4x
//   B: bilinear tables
//   C: producer/consumer (waves 0-7 gather, 8-15 MFMA), unchanged from r8
// ---------------------------------------------------------------------------
struct PhaseC {
  f32x4 swgtv[18 * 64];
  i32x4 slinv[18 * 64];
  __bf16 atile[2][64 * 128];
};
union FusedLDS {
  __bf16 rowbuf[3 * 66 * 256];
  PhaseC c;
};

__global__ __launch_bounds__(1024) void fused_kernel(
    const __bf16* __restrict__ xT, const __bf16* __restrict__ wFragD,
    const __bf16* __restrict__ wFragO, const float* __restrict__ b_off,
    const float* __restrict__ sc, const float* __restrict__ sh,
    float* __restrict__ out) {
  __shared__ __attribute__((aligned(16))) FusedLDS U;
  __shared__ float omrow[54 * 64];
  int t = threadIdx.x;
  int b = blockIdx.x >> 6, y = blockIdx.x & 63;
  int lane = t & 63, wv = t >> 6;
  int l15 = lane & 15, quad = lane >> 4;
  const __bf16* xTb = xT + (size_t)b * 64 * 64 * 256;
  bf16x8 z8;
  #pragma unroll
  for (int e = 0; e < 8; ++e) z8[e] = (__bf16)0.f;

  // ---- phase A: stage rowbuf[dy][px66][ch] ----
  for (int i = t; i < 3 * 66 * 32; i += 1024) {
    int c = i & 31, px66 = (i >> 5) % 66, dy = i / 2112;
    int y2 = y + dy - 1, x2 = px66 - 1;
    bf16x8 v = z8;
    if (y2 >= 0 && y2 < 64 && x2 >= 0 && x2 < 64)
      v = *(const bf16x8*)(xTb + ((size_t)y2 * 64 + x2) * 256 + c * 8);
    *(bf16x8*)&U.rowbuf[dy * 16896 + px66 * 256 + ((c ^ (px66 & 7)) * 8)] = v;
  }
  __syncthreads();

  // offset-conv: 4 waves only (wv = ocq), 4 M-frags per wave.
  // B-frags loaded once per block; accumulation order per (oc,px) identical
  // to r8 (taps outer, kc inner) -> bitwise-same omrow.
  if (wv < 4) {
    int ocq = wv;
    f32x4 acc4[4];
    #pragma unroll
    for (int fm = 0; fm < 4; ++fm) acc4[fm] = (f32x4){0.f, 0.f, 0.f, 0.f};
    for (int tap = 0; tap < 9; ++tap) {
      int dy = tap / 3, dxs = tap % 3;
      const __bf16* bb = wFragO + ((size_t)(tap * 8) * 4 + ocq) * 512 + lane * 8;
      const __bf16* rb = U.rowbuf + dy * 16896;
      #pragma unroll
      for (int kc = 0; kc < 8; ++kc) {
        bf16x8 Bf = *(const bf16x8*)(bb + (size_t)kc * 4 * 512);
        int c = kc * 4 + quad;
        #pragma unroll
        for (int fm = 0; fm < 4; ++fm) {
          int p0 = fm * 16 + l15 + dxs;
          bf16x8 a0 = *(const bf16x8*)&rb[p0 * 256 + ((c ^ (p0 & 7)) * 8)];
          acc4[fm] = MFMA16(a0, Bf, acc4[fm]);
        }
      }
    }
    int oc = ocq * 16 + l15;
    if (oc < 54) {
      float bo = b_off[oc];
      #pragma unroll
      for (int fm = 0; fm < 4; ++fm) {
        f32x4 r = {acc4[fm].x + bo, acc4[fm].y + bo,
                   acc4[fm].z + bo, acc4[fm].w + bo};
        *(f32x4*)&omrow[oc * 64 + fm * 16 + quad * 4] = r;
      }
    }
  }
  __syncthreads();                        // omrow ready; rowbuf dead

  // ---- phase B: bilinear corner tables ----
  for (int i = t; i < 18 * 64; i += 1024) {
    int gk = i >> 6, p = i & 63;
    int k = gk % 9;
    float oy = omrow[gk * 64 + p];
    float ox = omrow[(18 + gk) * 64 + p];
    float mz = omrow[(36 + gk) * 64 + p];
    float mv = 1.f / (1.f + expf(-mz));
    float py  = (float)(y + (k / 3) - 1) + oy;
    float pxf = (float)(p + (k % 3) - 1) + ox;
    float y0f = floorf(py), x0f = floorf(pxf);
    int y0 = (int)y0f, x0 = (int)x0f;
    float ly = py - y0f, lx = pxf - x0f;
    int y1 = y0 + 1, x1 = x0 + 1;
    bool vy0 = (y0 >= 0) && (y0 < 64), vy1 = (y1 >= 0) && (y1 < 64);
    bool vx0 = (x0 >= 0) && (x0 < 64), vx1 = (x1 >= 0) && (x1 < 64);
    int cy0 = min(max(y0, 0), 63), cy1 = min(max(y1, 0), 63);
    int cx0 = min(max(x0, 0), 63), cx1 = min(max(x1, 0), 63);
    f32x4 sv;
    sv.x = (vy0 && vx0) ? (1.f - ly) * (1.f - lx) * mv : 0.f;
    sv.y = (vy0 && vx1) ? (1.f - ly) * lx * mv : 0.f;
    sv.z = (vy1 && vx0) ? ly * (1.f - lx) * mv : 0.f;
    sv.w = (vy1 && vx1) ? ly * lx * mv : 0.f;
    i32x4 lv;
    lv.x = (cy0 * 64 + cx0) * 256;
    lv.y = (cy0 * 64 + cx1) * 256;
    lv.z = (cy1 * 64 + cx0) * 256;
    lv.w = (cy1 * 64 + cx1) * 256;
    U.c.swgtv[i] = sv;
    U.c.slinv[i] = lv;
  }
  __syncthreads();                        // tables visible; atile region free

  // ---- phase C prologue: all 1024 threads gather tap 0 (1 chunk each) ----
  {
    int p = t >> 4, c16 = t & 15;
    const __bf16* xg = xTb + c16 * 8;     // tap 0 -> group 0
    f32x4 sv = U.c.swgtv[p];
    i32x4 lv = U.c.slinv[p];
    bf16x8 c0 = *(const bf16x8*)(xg + lv.x);
    bf16x8 c1 = *(const bf16x8*)(xg + lv.y);
    bf16x8 c2 = *(const bf16x8*)(xg + lv.z);
    bf16x8 c3 = *(const bf16x8*)(xg + lv.w);
    bf16x8 o;
    #pragma unroll
    for (int e = 0; e < 8; ++e)
      o[e] = (__bf16)(sv.x * (float)c0[e] + sv.y * (float)c1[e]
                    + sv.z * (float)c2[e] + sv.w * (float)c3[e]);
    *(bf16x8*)&U.c.atile[0][ATIDX(p, c16)] = o;
  }

  f32x4 acc[4][2];
  #pragma unroll
  for (int fm = 0; fm < 4; ++fm) {
    acc[fm][0] = (f32x4){0.f, 0.f, 0.f, 0.f};
    acc[fm][1] = (f32x4){0.f, 0.f, 0.f, 0.f};
  }
  int nq = wv - 8;
  bf16x8 bn0, bn1;
  if (wv >= 8) {                          // consumer: rolling B prefetch (idx 0)
    const __bf16* bb = wFragD + ((size_t)nq * 2) * 512 + lane * 8;
    bn0 = *(const bf16x8*)bb;
    bn1 = *(const bf16x8*)(bb + 512);
  }
  __syncthreads();                        // atile[0] (tap 0) ready

  // ---- phase C main loop: 1 tap per barrier; producers gather gk+1 ----
  for (int gk = 0; gk < 18; ++gk) {
    if (wv < 8) {
      if (gk < 17) {
        int gn = gk + 1;
        int c16 = t & 15, p = t >> 4;     // p in [0,32); also handles p+32
        const __bf16* xg = xTb + (gn / 9) * 128 + c16 * 8;
        __bf16* dst = U.c.atile[(gk + 1) & 1];
        #pragma unroll
        for (int half = 0; half < 2; ++half) {
          int pp = p + half * 32;
          f32x4 sv = U.c.swgtv[gn * 64 + pp];
          i32x4 lv = U.c.slinv[gn * 64 + pp];
          bf16x8 c0 = *(const bf16x8*)(xg + lv.x);
          bf16x8 c1 = *(const bf16x8*)(xg + lv.y);
          bf16x8 c2 = *(const bf16x8*)(xg + lv.z);
          bf16x8 c3 = *(const bf16x8*)(xg + lv.w);
          bf16x8 o;
          #pragma unroll
          for (int e = 0; e < 8; ++e)
            o[e] = (__bf16)(sv.x * (float)c0[e] + sv.y * (float)c1[e]
                          + sv.z * (float)c2[e] + sv.w * (float)c3[e]);
          *(bf16x8*)&dst[ATIDX(pp, c16)] = o;
        }
      }
    } else {
      const __bf16* at = U.c.atile[gk & 1];
      #pragma unroll
      for (int kc = 0; kc < 4; ++kc) {
        bf16x8 b0 = bn0, b1 = bn1;
        int nidx = gk * 4 + kc + 1;
        if (nidx < 72) {                  // prefetch next B pair
          const __bf16* bb = wFragD + ((size_t)nidx * 16 + nq * 2) * 512 + lane * 8;
          bn0 = *(const bf16x8*)bb;
          bn1 = *(const bf16x8*)(bb + 512);
        }
        #pragma unroll
        for (int fm = 0; fm < 4; ++fm) {
          bf16x8 a = *(const bf16x8*)&at[ATIDX(fm * 16 + l15, kc * 4 + quad)];
          acc[fm][0] = MFMA16(a, b0, acc[fm][0]);
          acc[fm][1] = MFMA16(a, b1, acc[fm][1]);
        }
      }
    }
    __syncthreads();
  }

  // ---- epilogue: consumers write BN+ReLU output ----
  if (wv >= 8) {
    #pragma unroll
    for (int fm = 0; fm < 4; ++fm) {
      #pragma unroll
      for (int fn = 0; fn < 2; ++fn) {
        int oc = nq * 32 + fn * 16 + l15;
        float s = sc[oc], h = sh[oc];
        f32x4 v = acc[fm][fn];
        f32x4 r = {fmaxf(v.x * s + h, 0.f), fmaxf(v.y * s + h, 0.f),
                   fmaxf(v.z * s + h, 0.f), fmaxf(v.w * s + h, 0.f)};
        int pxs = fm * 16 + quad * 4;
        *(f32x4*)(out + (((size_t)b * 256 + oc) * 64 + y) * 64 + pxs) = r;
      }
    }
  }
}

// ---------------------------------------------------------------------------
extern "C" void kernel_launch(void* const* d_in, const int* in_sizes, int n_in,
                              void* d_out, int out_size, void* d_ws, size_t ws_size,
                              hipStream_t stream) {
  const float* x     = (const float*)d_in[0];
  const float* w_off = (const float*)d_in[1];
  const float* b_off = (const float*)d_in[2];
  const float* w     = (const float*)d_in[3];
  const float* bconv = (const float*)d_in[4];
  const float* gamma = (const float*)d_in[5];
  const float* beta  = (const float*)d_in[6];
  const float* rmean = (const float*)d_in[7];
  const float* rvar  = (const float*)d_in[8];
  float* out = (float*)d_out;

  __bf16* xT     = (__bf16*)d_ws;                          // 8,388,608 B
  __bf16* wFragD = (__bf16*)((char*)d_ws + 8388608);       // 1,179,648 B
  __bf16* wFragO = (__bf16*)((char*)d_ws + 9568256);       //   294,912 B
  float*  sc     = (float*)((char*)d_ws + 9863168);
  float*  sh     = (float*)((char*)d_ws + 9864192);

  setup_kernel<<<1024 + 2880, 256, 0, stream>>>(
      x, w, w_off, bconv, gamma, beta, rmean, rvar, xT, wFragD, wFragO, sc, sh);
  fused_kernel<<<4 * 64, 1024, 0, stream>>>(xT, wFragD, wFragO, b_off, sc, sh, out);
}